// Round 5
// baseline (1219.575 us; speedup 1.0000x reference)
//
#include <hip/hip_runtime.h>
#include <cfloat>
#include <cstddef>

// ---------------------------------------------------------------------------
// SemanticRQVAE forward, round 4: register-only MFMA K-loops with explicit
// static deep-prefetch pipeline (A ring depth 3, B ring depth 2, full unroll).
// Rationale: R2/R3 were HBM-latency-bound on A (18% MfmaUtil == 192cyc MFMA
// per ~1100cyc A-latency round trip). No LDS, no K-loop barriers.
// d_out layout (floats): recon (25165824) | indices as float (262144)
//                        | recon_loss | commit_loss
// ---------------------------------------------------------------------------

#define BATCH   65536
#define EDIM    384
#define HDIM    512
#define NCODE   256
#define NQ      4

#define OUT_IDX_OFF 25165824          // BATCH*EDIM
#define OUT_RL_OFF  25427968          // + BATCH*4
#define WS_BUFA     0
#define WS_BUFB     33554432
#define WS_CBSPL    67108864
#define WS_CNORM    67633152
#define WS_COMMITP  67634176
#define WS_RECONP   67636224
#define WS_W1S      67637760          // 384*512 floats
#define WS_W2S      67834368          // 512*512
#define WS_W3S      68096512          // 512*512
#define WS_W4S      68358656          // 512*384  (ends 68555264)

typedef _Float16 half8 __attribute__((ext_vector_type(8)));
typedef float    f32x16 __attribute__((ext_vector_type(16)));

__device__ __forceinline__ void cvt_hl(const float4& a0, const float4& a1,
                                       half8& h, half8& l)
{
    float vs[8] = {a0.x, a0.y, a0.z, a0.w, a1.x, a1.y, a1.z, a1.w};
#pragma unroll
    for (int j = 0; j < 8; ++j) {
        _Float16 hv = (_Float16)vs[j];
        h[j] = hv;
        l[j] = (_Float16)(vs[j] - (float)hv);
    }
}

// ---------------------------------------------------------------------------
// Split f32 weight W[K][N] into f16 hi/lo, tile-ready u16 layout:
//   entry(kt, hl, khalf, col) = ((kt*2 + hl)*2 + khalf)*N + col, 8 u16 each
//   holding k = kt*16 + khalf*8 + j.
// ---------------------------------------------------------------------------
__global__ __launch_bounds__(256)
void split_w(const float* __restrict__ W, unsigned short* __restrict__ out,
             int N, int K)
{
    int u = blockIdx.x * 256 + threadIdx.x;
    int col  = u % N;
    int rem  = u / N;
    int khalf = rem & 1;
    int kt    = rem >> 1;
    int kbase = kt * 16 + khalf * 8;
    half8 h, l;
#pragma unroll
    for (int j = 0; j < 8; ++j) {
        float v = W[(size_t)(kbase + j) * N + col];
        _Float16 hv = (_Float16)v;
        h[j] = hv;
        l[j] = (_Float16)(v - (float)hv);
    }
    size_t eh = ((size_t)(kt * 4 + khalf)) * N + col;        // hl=0
    size_t el = ((size_t)(kt * 4 + 2 + khalf)) * N + col;    // hl=1
    *reinterpret_cast<half8*>(out + eh * 8) = h;
    *reinterpret_cast<half8*>(out + el * 8) = l;
}

// ---------------------------------------------------------------------------
// Register-only MFMA GEMM with static deep prefetch.
// Block: 128 rows x BN cols, 4 waves. BN=256 -> waves 2x2 (64x128 each);
// BN=128 -> waves 4x1 (32x128 each). K-loop fully unrolled (NKT k-tiles of
// 16); A ring depth 3, B ring depth 2 (all indices compile-time constants).
// ---------------------------------------------------------------------------
template <int BN, int NKT, bool RELU, bool LOSS>
__global__ __launch_bounds__(256, 1)
void gemm_reg(const float* __restrict__ A, const unsigned short* __restrict__ Wsp,
              const float* __restrict__ bias, float* __restrict__ C,
              const float* __restrict__ X, float* __restrict__ lossP,
              int N)
{
    constexpr int WN = BN / 128;          // waves along N
    constexpr int WM = 4 / WN;            // waves along M
    constexpr int MR = 128 / WM;          // rows per wave
    constexpr int FM = MR / 32;           // 32-row frags per wave
    constexpr int K  = NKT * 16;
    constexpr int DA = 3;                 // A prefetch depth (k-tiles)
    constexpr int DB = 2;                 // B prefetch depth

    const int tid  = threadIdx.x;
    const int wid  = tid >> 6;
    const int lane = tid & 63;
    const int l31  = lane & 31;
    const int lh   = lane >> 5;
    const int wm   = wid / WN;
    const int wn   = wid % WN;
    const int row0 = blockIdx.y * 128;
    const int n0   = blockIdx.x * BN;

    f32x16 acc[FM][4];
#pragma unroll
    for (int m = 0; m < FM; ++m)
#pragma unroll
        for (int n = 0; n < 4; ++n) acc[m][n] = (f32x16)(0.0f);

    const float* ap[FM];
#pragma unroll
    for (int fm = 0; fm < FM; ++fm)
        ap[fm] = A + (size_t)(row0 + wm * MR + fm * 32 + l31) * K + lh * 8;

    const half8* b8 = reinterpret_cast<const half8*>(Wsp);
    const int colb = n0 + wn * 128 + l31;

    // ---- static prefetch rings ----
    float4 ar0[DA][FM], ar1[DA][FM];
    half8  brh[DB][4], brl[DB][4];

#pragma unroll
    for (int p = 0; p < DA; ++p)
#pragma unroll
        for (int fm = 0; fm < FM; ++fm) {
            ar0[p][fm] = *reinterpret_cast<const float4*>(ap[fm] + p * 16);
            ar1[p][fm] = *reinterpret_cast<const float4*>(ap[fm] + p * 16 + 4);
        }
#pragma unroll
    for (int p = 0; p < DB; ++p) {
        const size_t eh = (size_t)(p * 4 + lh) * N + colb;
        const size_t el = (size_t)(p * 4 + 2 + lh) * N + colb;
#pragma unroll
        for (int nt = 0; nt < 4; ++nt) {
            brh[p][nt] = b8[eh + nt * 32];
            brl[p][nt] = b8[el + nt * 32];
        }
    }

#pragma unroll
    for (int kt = 0; kt < NKT; ++kt) {
        const int sa = kt % DA;
        const int sb = kt % DB;

        // consume A slot -> f16 h/l
        half8 Ah[FM], Al[FM];
#pragma unroll
        for (int fm = 0; fm < FM; ++fm)
            cvt_hl(ar0[sa][fm], ar1[sa][fm], Ah[fm], Al[fm]);
        // reissue A slot
        if (kt + DA < NKT) {
#pragma unroll
            for (int fm = 0; fm < FM; ++fm) {
                ar0[sa][fm] = *reinterpret_cast<const float4*>(ap[fm] + (kt + DA) * 16);
                ar1[sa][fm] = *reinterpret_cast<const float4*>(ap[fm] + (kt + DA) * 16 + 4);
            }
        }
        // grab B regs (renamed locals), reissue B slot
        half8 Bh[4], Bl[4];
#pragma unroll
        for (int nt = 0; nt < 4; ++nt) { Bh[nt] = brh[sb][nt]; Bl[nt] = brl[sb][nt]; }
        if (kt + DB < NKT) {
            const size_t eh = (size_t)((kt + DB) * 4 + lh) * N + colb;
            const size_t el = (size_t)((kt + DB) * 4 + 2 + lh) * N + colb;
#pragma unroll
            for (int nt = 0; nt < 4; ++nt) {
                brh[sb][nt] = b8[eh + nt * 32];
                brl[sb][nt] = b8[el + nt * 32];
            }
        }
        // MFMAs (order per accumulator identical to rounds 1-3)
#pragma unroll
        for (int nt = 0; nt < 4; ++nt)
#pragma unroll
            for (int fm = 0; fm < FM; ++fm) {
                acc[fm][nt] = __builtin_amdgcn_mfma_f32_32x32x16_f16(Ah[fm], Bh[nt], acc[fm][nt], 0, 0, 0);
                acc[fm][nt] = __builtin_amdgcn_mfma_f32_32x32x16_f16(Ah[fm], Bl[nt], acc[fm][nt], 0, 0, 0);
                acc[fm][nt] = __builtin_amdgcn_mfma_f32_32x32x16_f16(Al[fm], Bh[nt], acc[fm][nt], 0, 0, 0);
            }
    }

    // epilogue: bias (+relu) (+loss) + stores
    float lacc = 0.f;
#pragma unroll
    for (int fm = 0; fm < FM; ++fm) {
#pragma unroll
        for (int nt = 0; nt < 4; ++nt) {
            const int col = n0 + wn * 128 + nt * 32 + l31;
            const float b = bias[col];
#pragma unroll
            for (int rg = 0; rg < 16; ++rg) {
                const int row = row0 + wm * MR + fm * 32 + (rg & 3) + 8 * (rg >> 2) + 4 * lh;
                float v = acc[fm][nt][rg] + b;
                if (RELU) v = v > 0.f ? v : 0.f;
                C[(size_t)row * N + col] = v;
                if constexpr (LOSS) {
                    float d = v - X[(size_t)row * N + col];
                    lacc = fmaf(d, d, lacc);
                }
            }
        }
    }

    if constexpr (LOSS) {
        __shared__ float red[256];
        red[tid] = lacc;
        __syncthreads();
        for (int s = 128; s > 0; s >>= 1) {
            if (tid < s) red[tid] += red[tid + s];
            __syncthreads();
        }
        if (tid == 0) lossP[blockIdx.y * gridDim.x + blockIdx.x] = red[0];
    }
}

// ---------------------------------------------------------------------------
// codebook squared norms (exact f32)
// ---------------------------------------------------------------------------
__global__ __launch_bounds__(64)
void cnorm_kernel(const float* __restrict__ cb, float* __restrict__ cnorm)
{
    const int code = blockIdx.x;
    const int lane = threadIdx.x;
    const float* r = cb + (size_t)code * HDIM;
    float s = 0.f;
    for (int k = lane; k < HDIM; k += 64) s = fmaf(r[k], r[k], s);
#pragma unroll
    for (int off = 32; off > 0; off >>= 1) s += __shfl_down(s, off);
    if (lane == 0) cnorm[code] = s;
}

// ---------------------------------------------------------------------------
// Split f32 codebook into f16 hi/lo tile-ready layout.
// ---------------------------------------------------------------------------
__global__ __launch_bounds__(256)
void split_cb(const float* __restrict__ cb, unsigned short* __restrict__ out)
{
    int u = blockIdx.x * 256 + threadIdx.x;
    int q    = u >> 14;
    int rem  = u & 16383;
    int code = rem >> 6;
    int kt   = (rem >> 1) & 31;
    int khalf = rem & 1;
    int k = kt * 16 + khalf * 8;
    const float* p = cb + ((size_t)(q * NCODE + code)) * HDIM + k;
    float4 v0 = *reinterpret_cast<const float4*>(p);
    float4 v1 = *reinterpret_cast<const float4*>(p + 4);
    half8 h, l;
    cvt_hl(v0, v1, h, l);
    size_t o = (size_t)(q * 32 + kt) * 8192 + (size_t)khalf * 2048 + (size_t)code * 8;
    *reinterpret_cast<half8*>(out + o)        = h;
    *reinterpret_cast<half8*>(out + o + 4096) = l;
}

// ---------------------------------------------------------------------------
// One residual-VQ stage, register-only score GEMM with the same static
// deep-prefetch pipeline. Argmax / residual-update / commit unchanged.
// ---------------------------------------------------------------------------
template <bool LAST>
__global__ __launch_bounds__(256, 1)
void vq_stage(int q,
              const float* __restrict__ Rin, float* __restrict__ Rout,
              const float* __restrict__ zsrc,
              const unsigned short* __restrict__ cbs,
              const float* __restrict__ cb,
              const float* __restrict__ cnorm,
              float* __restrict__ idx_out,
              float* __restrict__ commitP)
{
    constexpr int DA = 3;
    constexpr int DB = 2;
    constexpr int NKT = 32;

    __shared__ float sval[2][128];
    __shared__ int   sidx[2][128];
    __shared__ int   idxbuf[128];
    __shared__ float red[256];

    const int tid  = threadIdx.x;
    const int wid  = tid >> 6;
    const int lane = tid & 63;
    const int l31  = lane & 31;
    const int lh   = lane >> 5;
    const int wm   = wid >> 1;
    const int wn   = wid & 1;
    const int row0 = blockIdx.x * 128;

    f32x16 acc[2][4];
#pragma unroll
    for (int m = 0; m < 2; ++m)
#pragma unroll
        for (int n = 0; n < 4; ++n) acc[m][n] = (f32x16)(0.0f);

    const float* ap[2];
#pragma unroll
    for (int fm = 0; fm < 2; ++fm)
        ap[fm] = Rin + (size_t)(row0 + wm * 64 + fm * 32 + l31) * HDIM + lh * 8;

    const half8* c8 = reinterpret_cast<const half8*>(cbs);
    const size_t qbase = (size_t)q * 32 * 1024;
    const int code_b = wn * 128 + l31;

    float4 ar0[DA][2], ar1[DA][2];
    half8  brh[DB][4], brl[DB][4];

#pragma unroll
    for (int p = 0; p < DA; ++p)
#pragma unroll
        for (int fm = 0; fm < 2; ++fm) {
            ar0[p][fm] = *reinterpret_cast<const float4*>(ap[fm] + p * 16);
            ar1[p][fm] = *reinterpret_cast<const float4*>(ap[fm] + p * 16 + 4);
        }
#pragma unroll
    for (int p = 0; p < DB; ++p) {
        const size_t eh = qbase + (size_t)p * 1024 + (size_t)lh * 256 + code_b;
#pragma unroll
        for (int nt = 0; nt < 4; ++nt) {
            brh[p][nt] = c8[eh + nt * 32];
            brl[p][nt] = c8[eh + 512 + nt * 32];
        }
    }

#pragma unroll
    for (int kt = 0; kt < NKT; ++kt) {
        const int sa = kt % DA;
        const int sb = kt % DB;

        half8 Ah[2], Al[2];
#pragma unroll
        for (int fm = 0; fm < 2; ++fm)
            cvt_hl(ar0[sa][fm], ar1[sa][fm], Ah[fm], Al[fm]);
        if (kt + DA < NKT) {
#pragma unroll
            for (int fm = 0; fm < 2; ++fm) {
                ar0[sa][fm] = *reinterpret_cast<const float4*>(ap[fm] + (kt + DA) * 16);
                ar1[sa][fm] = *reinterpret_cast<const float4*>(ap[fm] + (kt + DA) * 16 + 4);
            }
        }
        half8 Bh[4], Bl[4];
#pragma unroll
        for (int nt = 0; nt < 4; ++nt) { Bh[nt] = brh[sb][nt]; Bl[nt] = brl[sb][nt]; }
        if (kt + DB < NKT) {
            const size_t eh = qbase + (size_t)(kt + DB) * 1024 + (size_t)lh * 256 + code_b;
#pragma unroll
            for (int nt = 0; nt < 4; ++nt) {
                brh[sb][nt] = c8[eh + nt * 32];
                brl[sb][nt] = c8[eh + 512 + nt * 32];
            }
        }
#pragma unroll
        for (int nt = 0; nt < 4; ++nt)
#pragma unroll
            for (int fm = 0; fm < 2; ++fm) {
                acc[fm][nt] = __builtin_amdgcn_mfma_f32_32x32x16_f16(Ah[fm], Bh[nt], acc[fm][nt], 0, 0, 0);
                acc[fm][nt] = __builtin_amdgcn_mfma_f32_32x32x16_f16(Ah[fm], Bl[nt], acc[fm][nt], 0, 0, 0);
                acc[fm][nt] = __builtin_amdgcn_mfma_f32_32x32x16_f16(Al[fm], Bh[nt], acc[fm][nt], 0, 0, 0);
            }
    }

    // ---- scores + per-row argmax (first-max tie-break) ----
    const float* cn = cnorm + q * NCODE;
#pragma unroll
    for (int Mt = 0; Mt < 2; ++Mt) {
#pragma unroll
        for (int rg = 0; rg < 16; ++rg) {
            float bv = -FLT_MAX;
            int   bi = 0;
#pragma unroll
            for (int nt = 0; nt < 4; ++nt) {
                const int code = wn * 128 + nt * 32 + l31;
                float s = 2.f * acc[Mt][nt][rg] - cn[code];
                if (s > bv || (s == bv && code < bi)) { bv = s; bi = code; }
            }
#pragma unroll
            for (int m = 1; m < 32; m <<= 1) {
                float ov = __shfl_xor(bv, m, 64);
                int   oi = __shfl_xor(bi, m, 64);
                if (ov > bv || (ov == bv && oi < bi)) { bv = ov; bi = oi; }
            }
            if (l31 == 0) {
                int row = wm * 64 + Mt * 32 + (rg & 3) + 8 * (rg >> 2) + 4 * lh;
                sval[wn][row] = bv;
                sidx[wn][row] = bi;
            }
        }
    }
    __syncthreads();
    if (tid < 128) {
        float v0 = sval[0][tid], v1 = sval[1][tid];
        int   i0 = sidx[0][tid], i1 = sidx[1][tid];
        int b = (v1 > v0 || (v1 == v0 && i1 < i0)) ? i1 : i0;
        idxbuf[tid] = b;
        idx_out[(size_t)(row0 + tid) * NQ + q] = (float)b;
    }
    __syncthreads();

    // ---- residual update (+ commit partial; LAST: quant = z - R') ----
    float ca = 0.f;
    const int rgrp = tid >> 3;
    const int lpos = tid & 7;
#pragma unroll
    for (int rr = 0; rr < 4; ++rr) {
        const int row = rr * 32 + rgrp;
        const float* rin  = Rin + (size_t)(row0 + row) * HDIM;
        const float* crow = cb + ((size_t)q * NCODE + idxbuf[row]) * HDIM;
        float* rout = Rout + (size_t)(row0 + row) * HDIM;
        const float* zr = LAST ? (zsrc + (size_t)(row0 + row) * HDIM) : nullptr;
#pragma unroll
        for (int j = 0; j < 16; ++j) {
            const int f4 = lpos + j * 8;
            float4 rv = *reinterpret_cast<const float4*>(rin + f4 * 4);
            float4 cv = *reinterpret_cast<const float4*>(crow + f4 * 4);
            float4 d;
            d.x = rv.x - cv.x; d.y = rv.y - cv.y;
            d.z = rv.z - cv.z; d.w = rv.w - cv.w;
            ca = fmaf(d.x, d.x, ca); ca = fmaf(d.y, d.y, ca);
            ca = fmaf(d.z, d.z, ca); ca = fmaf(d.w, d.w, ca);
            if constexpr (LAST) {
                float4 zv = *reinterpret_cast<const float4*>(zr + f4 * 4);
                float4 qv;
                qv.x = zv.x - d.x; qv.y = zv.y - d.y;
                qv.z = zv.z - d.z; qv.w = zv.w - d.w;
                *reinterpret_cast<float4*>(rout + f4 * 4) = qv;
            } else {
                *reinterpret_cast<float4*>(rout + f4 * 4) = d;
            }
        }
    }

    red[tid] = ca;
    __syncthreads();
    for (int s = 128; s > 0; s >>= 1) {
        if (tid < s) red[tid] += red[tid + s];
        __syncthreads();
    }
    if (tid == 0) commitP[q * 512 + blockIdx.x] = red[0];
}

// ---------------------------------------------------------------------------
// deterministic final loss reduction
// ---------------------------------------------------------------------------
__global__ __launch_bounds__(256)
void loss_reduce(const float* __restrict__ cP, int nc,
                 const float* __restrict__ rP, int nr,
                 float* __restrict__ out2)
{
    __shared__ float red[256];
    const int tid = threadIdx.x;

    float s = 0.f;
    for (int i = tid; i < nc; i += 256) s += cP[i];
    red[tid] = s;
    __syncthreads();
    for (int st = 128; st > 0; st >>= 1) {
        if (tid < st) red[tid] += red[tid + st];
        __syncthreads();
    }
    float ctot = red[0];
    __syncthreads();

    s = 0.f;
    for (int i = tid; i < nr; i += 256) s += rP[i];
    red[tid] = s;
    __syncthreads();
    for (int st = 128; st > 0; st >>= 1) {
        if (tid < st) red[tid] += red[tid + st];
        __syncthreads();
    }
    if (tid == 0) {
        out2[0] = red[0] / ((float)BATCH * (float)EDIM);
        out2[1] = 0.25f * ctot / ((float)BATCH * (float)HDIM);
    }
}

// ---------------------------------------------------------------------------
extern "C" void kernel_launch(void* const* d_in, const int* in_sizes, int n_in,
                              void* d_out, int out_size, void* d_ws, size_t ws_size,
                              hipStream_t stream)
{
    const float* x   = (const float*)d_in[0];
    const float* ew1 = (const float*)d_in[1];
    const float* eb1 = (const float*)d_in[2];
    const float* ew2 = (const float*)d_in[3];
    const float* eb2 = (const float*)d_in[4];
    const float* cb  = (const float*)d_in[5];
    const float* dw1 = (const float*)d_in[6];
    const float* db1 = (const float*)d_in[7];
    const float* dw2 = (const float*)d_in[8];
    const float* db2 = (const float*)d_in[9];

    float* out  = (float*)d_out;
    float* ws   = (float*)d_ws;
    float* bufA = ws + WS_BUFA;
    float* bufB = ws + WS_BUFB;
    unsigned short* cbs = (unsigned short*)(ws + WS_CBSPL);
    float* cn   = ws + WS_CNORM;
    float* cP   = ws + WS_COMMITP;
    float* rP   = ws + WS_RECONP;
    unsigned short* w1s = (unsigned short*)(ws + WS_W1S);
    unsigned short* w2s = (unsigned short*)(ws + WS_W2S);
    unsigned short* w3s = (unsigned short*)(ws + WS_W3S);
    unsigned short* w4s = (unsigned short*)(ws + WS_W4S);

    // one-shot prep: codebook norms + all f16 hi/lo splits
    cnorm_kernel<<<NQ * NCODE, 64, 0, stream>>>(cb, cn);
    split_cb<<<256, 256, 0, stream>>>(cb, cbs);
    split_w<<<(EDIM / 16) * 2 * HDIM / 256, 256, 0, stream>>>(ew1, w1s, HDIM, EDIM);
    split_w<<<(HDIM / 16) * 2 * HDIM / 256, 256, 0, stream>>>(ew2, w2s, HDIM, HDIM);
    split_w<<<(HDIM / 16) * 2 * HDIM / 256, 256, 0, stream>>>(dw1, w3s, HDIM, HDIM);
    split_w<<<(HDIM / 16) * 2 * EDIM / 256, 256, 0, stream>>>(dw2, w4s, EDIM, HDIM);

    // encoder (reg-only MFMA, deep prefetch)
    gemm_reg<256, 24, true, false><<<dim3(HDIM / 256, BATCH / 128), 256, 0, stream>>>(
        x, w1s, eb1, bufA, nullptr, nullptr, HDIM);
    gemm_reg<256, 32, false, false><<<dim3(HDIM / 256, BATCH / 128), 256, 0, stream>>>(
        bufA, w2s, eb2, bufB, nullptr, nullptr, HDIM);

    // residual VQ: 4 MFMA stages
    float* idxo = out + OUT_IDX_OFF;
    vq_stage<false><<<512, 256, 0, stream>>>(0, bufB, bufA, nullptr, cbs, cb, cn, idxo, cP);
    vq_stage<false><<<512, 256, 0, stream>>>(1, bufA, bufA, nullptr, cbs, cb, cn, idxo, cP);
    vq_stage<false><<<512, 256, 0, stream>>>(2, bufA, bufA, nullptr, cbs, cb, cn, idxo, cP);
    vq_stage<true ><<<512, 256, 0, stream>>>(3, bufA, bufB, bufB,    cbs, cb, cn, idxo, cP);

    // decoder (reg-only MFMA, deep prefetch)
    gemm_reg<256, 32, true, false><<<dim3(HDIM / 256, BATCH / 128), 256, 0, stream>>>(
        bufB, w3s, db1, bufA, nullptr, nullptr, HDIM);
    gemm_reg<128, 32, false, true><<<dim3(EDIM / 128, BATCH / 128), 256, 0, stream>>>(
        bufA, w4s, db2, out, x, rP, EDIM);

    // losses
    loss_reduce<<<1, 256, 0, stream>>>(cP, NQ * 512, rP,
                                       (BATCH / 128) * (EDIM / 128),
                                       out + OUT_RL_OFF);
}

// Round 7
// 989.562 us; speedup vs baseline: 1.2324x; 1.2324x over previous
//
#include <hip/hip_runtime.h>
#include <cfloat>
#include <cstddef>
#include <cstdint>

// ---------------------------------------------------------------------------
// SemanticRQVAE forward, round 6: counted-vmcnt pipeline, AMODE0-only.
// R5's failure was AMODE1's waitvm<12> no-op (B-tile race). Fix: pre-split x
// once (split_x) so ALL GEMMs + VQ stages use the verified AMODE0 pipeline:
// global_load_lds into a 3-buffer LDS ring, raw s_barrier + s_waitcnt
// vmcnt(6/4) (never 0 inside the loop).
// Activation format, per row, per k-tile of 16 (64 B):
//   [u=0] h(k0..7) [u=1] h(k8..15) [u=2] l(k0..7) [u=3] l(k8..15)
// d_out layout (floats): recon (25165824) | indices as float (262144)
//                        | recon_loss | commit_loss
// ws (floats): P0[33554432] | P1[33554432] (first 25.2M aliased as split-x)
//   | cbsplit | cnorm | commitP | reconP | w1s | w2s | w3s | w4s
// ---------------------------------------------------------------------------

#define BATCH   65536
#define EDIM    384
#define HDIM    512
#define NCODE   256
#define NQ      4

#define OUT_IDX_OFF 25165824
#define OUT_RL_OFF  25427968
#define WS_P0       0
#define WS_P1       33554432
#define WS_CBSPL    67108864
#define WS_CNORM    67633152
#define WS_COMMITP  67634176
#define WS_RECONP   67636224
#define WS_W1S      67637760
#define WS_W2S      67834368
#define WS_W3S      68096512
#define WS_W4S      68358656

typedef _Float16 half8 __attribute__((ext_vector_type(8)));
typedef float    f32x16 __attribute__((ext_vector_type(16)));

__device__ __forceinline__ void cvt_hl8(const float* vs, half8& h, half8& l)
{
#pragma unroll
    for (int j = 0; j < 8; ++j) {
        _Float16 hv = (_Float16)vs[j];
        h[j] = hv;
        l[j] = (_Float16)(vs[j] - (float)hv);
    }
}

__device__ __forceinline__ void gll16(const unsigned short* g, unsigned short* l)
{
    __builtin_amdgcn_global_load_lds(
        (const __attribute__((address_space(1))) unsigned int*)g,
        (__attribute__((address_space(3))) unsigned int*)l, 16, 0, 0);
}

template <int N> __device__ __forceinline__ void waitvm()
{
    __builtin_amdgcn_sched_barrier(0);
    if constexpr (N == 0)      asm volatile("s_waitcnt vmcnt(0)" ::: "memory");
    else if constexpr (N == 4) asm volatile("s_waitcnt vmcnt(4)" ::: "memory");
    else if constexpr (N == 6) asm volatile("s_waitcnt vmcnt(6)" ::: "memory");
    __builtin_amdgcn_sched_barrier(0);
}
__device__ __forceinline__ void barrier_raw()
{
    __builtin_amdgcn_s_barrier();
    __builtin_amdgcn_sched_barrier(0);
}

// ---------------------------------------------------------------------------
// One-shot splits
// ---------------------------------------------------------------------------
__global__ __launch_bounds__(256)
void split_x(const float* __restrict__ x, unsigned short* __restrict__ xs)
{
    int u = blockIdx.x * 256 + threadIdx.x;       // BATCH * 48 units
    int row = u / 48;
    int rem = u % 48;
    int kt = rem >> 1, khalf = rem & 1;
    const float* p = x + (size_t)row * EDIM + kt * 16 + khalf * 8;
    float vs[8];
#pragma unroll
    for (int j = 0; j < 8; ++j) vs[j] = p[j];
    half8 h, l;
    cvt_hl8(vs, h, l);
    unsigned short* o = xs + (size_t)row * 768 + kt * 32 + khalf * 8;
    *reinterpret_cast<half8*>(o)      = h;
    *reinterpret_cast<half8*>(o + 16) = l;
}

__global__ __launch_bounds__(256)
void split_w(const float* __restrict__ W, unsigned short* __restrict__ out,
             int N, int K)
{
    int u = blockIdx.x * 256 + threadIdx.x;
    int col  = u % N;
    int rem  = u / N;
    int khalf = rem & 1;
    int kt    = rem >> 1;
    int kbase = kt * 16 + khalf * 8;
    float vs[8];
#pragma unroll
    for (int j = 0; j < 8; ++j) vs[j] = W[(size_t)(kbase + j) * N + col];
    half8 h, l;
    cvt_hl8(vs, h, l);
    *reinterpret_cast<half8*>(out + ((size_t)(kt * 4 + khalf) * N + col) * 8)     = h;
    *reinterpret_cast<half8*>(out + ((size_t)(kt * 4 + 2 + khalf) * N + col) * 8) = l;
}

__global__ __launch_bounds__(256)
void split_cb(const float* __restrict__ cb, unsigned short* __restrict__ out)
{
    int u = blockIdx.x * 256 + threadIdx.x;
    int q    = u >> 14;
    int rem  = u & 16383;
    int code = rem >> 6;
    int kt   = (rem >> 1) & 31;
    int khalf = rem & 1;
    int k = kt * 16 + khalf * 8;
    const float* p = cb + ((size_t)(q * NCODE + code)) * HDIM + k;
    float vs[8];
#pragma unroll
    for (int j = 0; j < 8; ++j) vs[j] = p[j];
    half8 h, l;
    cvt_hl8(vs, h, l);
    size_t o = (size_t)(q * 32 + kt) * 8192 + (size_t)khalf * 2048 + (size_t)code * 8;
    *reinterpret_cast<half8*>(out + o)        = h;
    *reinterpret_cast<half8*>(out + o + 4096) = l;
}

__global__ __launch_bounds__(64)
void cnorm_kernel(const float* __restrict__ cb, float* __restrict__ cnorm)
{
    const int code = blockIdx.x;
    const int lane = threadIdx.x;
    const float* r = cb + (size_t)code * HDIM;
    float s = 0.f;
    for (int k = lane; k < HDIM; k += 64) s = fmaf(r[k], r[k], s);
#pragma unroll
    for (int off = 32; off > 0; off >>= 1) s += __shfl_down(s, off);
    if (lane == 0) cnorm[code] = s;
}

// ---------------------------------------------------------------------------
// Pipelined MFMA GEMM (AMODE0 only).
// A = split act (u16, row stride 2K), staged via global_load_lds.
// OMODE 0: C -> split act. OMODE 1: C -> f32 + recon loss vs X.
// Block 128 rows x BN cols, 4 waves. LDS: 3 buffers of (A 8KB + B BN*64B).
// ---------------------------------------------------------------------------
template <int BN, int NKT, int OMODE, bool RELU>
__global__ __launch_bounds__(256, 2)
void gemm_pl(const unsigned short* __restrict__ Ain,
             const unsigned short* __restrict__ Wsp,
             const float* __restrict__ bias, void* __restrict__ Cout,
             const float* __restrict__ X, float* __restrict__ lossP, int N)
{
    constexpr int WN  = BN / 128;
    constexpr int WM  = 4 / WN;
    constexpr int MR  = 128 / WM;
    constexpr int FM  = MR / 32;
    constexpr int K   = NKT * 16;
    constexpr int BOFF = 4096;                 // B offset (u16) within buffer
    constexpr int BUFU = 4096 + 4 * BN * 8;    // u16 per buffer
    constexpr int NIB = BN / 64;               // B gll instrs per wave
    constexpr int GPI = 2 + NIB;               // gll per wave per iter

    __shared__ __align__(16) unsigned short lds[3][BUFU];

    const int tid  = threadIdx.x;
    const int wid  = tid >> 6;
    const int lane = tid & 63;
    const int l31  = lane & 31;
    const int lh   = lane >> 5;
    const int wm   = wid / WN;
    const int wn   = wid % WN;
    const int row0 = blockIdx.y * 128;
    const int n0   = blockIdx.x * BN;

    f32x16 acc[FM][4];
#pragma unroll
    for (int m = 0; m < FM; ++m)
#pragma unroll
        for (int n = 0; n < 4; ++n) acc[m][n] = (f32x16)(0.0f);

    auto stageB = [&](int buf, int kt) {
        const unsigned short* img = Wsp + (size_t)kt * 4 * N * 8;
        unsigned short* dstb = &lds[buf][BOFF];
#pragma unroll
        for (int t = 0; t < NIB; ++t) {
            int e = (wid * NIB + t) * 64 + lane;
            int u = (BN == 256) ? (e >> 8) : (e >> 7);
            int c = e & (BN - 1);
            gll16(img + ((size_t)u * N + n0 + c) * 8, dstb + (size_t)e * 8);
        }
    };
    auto stageA = [&](int buf, int kt) {
#pragma unroll
        for (int t = 0; t < 2; ++t) {
            int i = wid * 2 + t;                  // 0..7
            int u = i >> 1, rh = i & 1;
            int row = rh * 64 + lane;
            gll16(Ain + (size_t)(row0 + row) * (2 * K) + kt * 32 + u * 8,
                  &lds[buf][(size_t)i * 512 + (size_t)lane * 8]);
        }
    };
    auto compute = [&](int buf) {
        const unsigned short* Ab = &lds[buf][0];
        const unsigned short* Bb = &lds[buf][BOFF];
        half8 Ah[FM], Al[FM];
#pragma unroll
        for (int fm = 0; fm < FM; ++fm) {
            int row = wm * MR + fm * 32 + l31;
            Ah[fm] = *reinterpret_cast<const half8*>(Ab + (size_t)lh * 1024 + (size_t)row * 8);
            Al[fm] = *reinterpret_cast<const half8*>(Ab + (size_t)(2 + lh) * 1024 + (size_t)row * 8);
        }
#pragma unroll
        for (int nt = 0; nt < 4; ++nt) {
            int col = wn * 128 + nt * 32 + l31;
            half8 Bh = *reinterpret_cast<const half8*>(Bb + (size_t)lh * BN * 8 + (size_t)col * 8);
            half8 Bl = *reinterpret_cast<const half8*>(Bb + (size_t)(2 + lh) * BN * 8 + (size_t)col * 8);
#pragma unroll
            for (int fm = 0; fm < FM; ++fm) {
                acc[fm][nt] = __builtin_amdgcn_mfma_f32_32x32x16_f16(Ah[fm], Bh, acc[fm][nt], 0, 0, 0);
                acc[fm][nt] = __builtin_amdgcn_mfma_f32_32x32x16_f16(Ah[fm], Bl, acc[fm][nt], 0, 0, 0);
                acc[fm][nt] = __builtin_amdgcn_mfma_f32_32x32x16_f16(Al[fm], Bh, acc[fm][nt], 0, 0, 0);
            }
        }
    };

    // prologue: stage kt0 -> buf0, kt1 -> buf1; drain to buf0
    stageA(0, 0); stageB(0, 0);
    stageA(1, 1); stageB(1, 1);
    waitvm<GPI>();
    barrier_raw();
    for (int kt = 0; kt < NKT; ++kt) {
        const int cur = kt % 3;
        if (kt + 2 < NKT) { const int nb = (kt + 2) % 3; stageA(nb, kt + 2); stageB(nb, kt + 2); }
        compute(cur);
        if (kt < NKT - 2) waitvm<GPI>(); else waitvm<0>();
        barrier_raw();
    }

    // ---- epilogue ----
    if constexpr (OMODE == 0) {
        unsigned short* o = (unsigned short*)Cout;
        const size_t rs = (size_t)N * 2;
#pragma unroll
        for (int fm = 0; fm < FM; ++fm) {
#pragma unroll
            for (int nt = 0; nt < 4; ++nt) {
                const int col = n0 + wn * 128 + nt * 32 + l31;
                const float b = bias[col];
                const size_t cbo = (size_t)(col >> 4) * 32 + (size_t)((col >> 3) & 1) * 8 + (col & 7);
#pragma unroll
                for (int rg = 0; rg < 16; ++rg) {
                    const int row = row0 + wm * MR + fm * 32 + (rg & 3) + 8 * (rg >> 2) + 4 * lh;
                    float v = acc[fm][nt][rg] + b;
                    if (RELU) v = v > 0.f ? v : 0.f;
                    _Float16 hv = (_Float16)v;
                    _Float16 lv = (_Float16)(v - (float)hv);
                    union { _Float16 f; unsigned short u; } ch, cl;
                    ch.f = hv; cl.f = lv;
                    o[(size_t)row * rs + cbo]      = ch.u;
                    o[(size_t)row * rs + cbo + 16] = cl.u;
                }
            }
        }
    } else {
        float* C = (float*)Cout;
        float lacc = 0.f;
#pragma unroll
        for (int fm = 0; fm < FM; ++fm) {
#pragma unroll
            for (int nt = 0; nt < 4; ++nt) {
                const int col = n0 + wn * 128 + nt * 32 + l31;
                const float b = bias[col];
#pragma unroll
                for (int rg = 0; rg < 16; ++rg) {
                    const int row = row0 + wm * MR + fm * 32 + (rg & 3) + 8 * (rg >> 2) + 4 * lh;
                    float v = acc[fm][nt][rg] + b;
                    if (RELU) v = v > 0.f ? v : 0.f;
                    C[(size_t)row * N + col] = v;
                    float d = v - X[(size_t)row * N + col];
                    lacc = fmaf(d, d, lacc);
                }
            }
        }
        __shared__ float red[256];
        red[tid] = lacc;
        __syncthreads();
        for (int s = 128; s > 0; s >>= 1) {
            if (tid < s) red[tid] += red[tid + s];
            __syncthreads();
        }
        if (tid == 0) lossP[blockIdx.y * gridDim.x + blockIdx.x] = red[0];
    }
}

// ---------------------------------------------------------------------------
// Residual-VQ stage (pipeline identical to gemm_pl AMODE0).
// ---------------------------------------------------------------------------
template <bool LAST>
__global__ __launch_bounds__(256, 2)
void vq_stage(int q,
              const unsigned short* __restrict__ Rin, unsigned short* __restrict__ Rout,
              const unsigned short* __restrict__ zsrc,
              const unsigned short* __restrict__ cbs,
              const float* __restrict__ cb,
              const float* __restrict__ cnorm,
              float* __restrict__ idx_out,
              float* __restrict__ commitP)
{
    constexpr int NKT = 32;
    __shared__ __align__(16) unsigned short lds[3][12288];
    __shared__ float sval[2][128];
    __shared__ int   sidx[2][128];
    __shared__ int   idxbuf[128];
    __shared__ float red[256];

    const int tid  = threadIdx.x;
    const int wid  = tid >> 6;
    const int lane = tid & 63;
    const int l31  = lane & 31;
    const int lh   = lane >> 5;
    const int wm   = wid >> 1;
    const int wn   = wid & 1;
    const int row0 = blockIdx.x * 128;

    f32x16 acc[2][4];
#pragma unroll
    for (int m = 0; m < 2; ++m)
#pragma unroll
        for (int n = 0; n < 4; ++n) acc[m][n] = (f32x16)(0.0f);

    auto stageA = [&](int buf, int kt) {
#pragma unroll
        for (int t = 0; t < 2; ++t) {
            int i = wid * 2 + t;
            int u = i >> 1, rh = i & 1;
            int row = rh * 64 + lane;
            gll16(Rin + (size_t)(row0 + row) * 1024 + kt * 32 + u * 8,
                  &lds[buf][(size_t)i * 512 + (size_t)lane * 8]);
        }
    };
    auto stageB = [&](int buf, int kt) {
        const unsigned short* img = cbs + (size_t)(q * 32 + kt) * 8192;
        unsigned short* dstb = &lds[buf][4096];
#pragma unroll
        for (int t = 0; t < 4; ++t) {
            int e = (wid * 4 + t) * 64 + lane;
            gll16(img + (size_t)e * 8, dstb + (size_t)e * 8);
        }
    };
    auto compute = [&](int buf) {
        const unsigned short* Ab = &lds[buf][0];
        const unsigned short* Bb = &lds[buf][4096];
        half8 Ah[2], Al[2];
#pragma unroll
        for (int fm = 0; fm < 2; ++fm) {
            int row = wm * 64 + fm * 32 + l31;
            Ah[fm] = *reinterpret_cast<const half8*>(Ab + (size_t)lh * 1024 + (size_t)row * 8);
            Al[fm] = *reinterpret_cast<const half8*>(Ab + (size_t)(2 + lh) * 1024 + (size_t)row * 8);
        }
#pragma unroll
        for (int nt = 0; nt < 4; ++nt) {
            int col = wn * 128 + nt * 32 + l31;
            half8 Bh = *reinterpret_cast<const half8*>(Bb + (size_t)lh * 2048 + (size_t)col * 8);
            half8 Bl = *reinterpret_cast<const half8*>(Bb + (size_t)(2 + lh) * 2048 + (size_t)col * 8);
#pragma unroll
            for (int fm = 0; fm < 2; ++fm) {
                acc[fm][nt] = __builtin_amdgcn_mfma_f32_32x32x16_f16(Ah[fm], Bh, acc[fm][nt], 0, 0, 0);
                acc[fm][nt] = __builtin_amdgcn_mfma_f32_32x32x16_f16(Ah[fm], Bl, acc[fm][nt], 0, 0, 0);
                acc[fm][nt] = __builtin_amdgcn_mfma_f32_32x32x16_f16(Al[fm], Bh, acc[fm][nt], 0, 0, 0);
            }
        }
    };

    stageA(0, 0); stageB(0, 0);
    stageA(1, 1); stageB(1, 1);
    waitvm<6>();
    barrier_raw();
    for (int kt = 0; kt < NKT; ++kt) {
        const int cur = kt % 3;
        if (kt + 2 < NKT) { const int nb = (kt + 2) % 3; stageA(nb, kt + 2); stageB(nb, kt + 2); }
        compute(cur);
        if (kt < NKT - 2) waitvm<6>(); else waitvm<0>();
        barrier_raw();
    }

    // ---- scores + per-row argmax (first-max tie-break) ----
    const float* cn = cnorm + q * NCODE;
#pragma unroll
    for (int Mt = 0; Mt < 2; ++Mt) {
#pragma unroll
        for (int rg = 0; rg < 16; ++rg) {
            float bv = -FLT_MAX;
            int   bi = 0;
#pragma unroll
            for (int nt = 0; nt < 4; ++nt) {
                const int code = wn * 128 + nt * 32 + l31;
                float s = 2.f * acc[Mt][nt][rg] - cn[code];
                if (s > bv || (s == bv && code < bi)) { bv = s; bi = code; }
            }
#pragma unroll
            for (int m = 1; m < 32; m <<= 1) {
                float ov = __shfl_xor(bv, m, 64);
                int   oi = __shfl_xor(bi, m, 64);
                if (ov > bv || (ov == bv && oi < bi)) { bv = ov; bi = oi; }
            }
            if (l31 == 0) {
                int row = wm * 64 + Mt * 32 + (rg & 3) + 8 * (rg >> 2) + 4 * lh;
                sval[wn][row] = bv;
                sidx[wn][row] = bi;
            }
        }
    }
    __syncthreads();
    if (tid < 128) {
        float v0 = sval[0][tid], v1 = sval[1][tid];
        int   i0 = sidx[0][tid], i1 = sidx[1][tid];
        int b = (v1 > v0 || (v1 == v0 && i1 < i0)) ? i1 : i0;
        idxbuf[tid] = b;
        idx_out[(size_t)(row0 + tid) * NQ + q] = (float)b;
    }
    __syncthreads();

    // ---- residual update on split storage (+ commit; LAST: quant = z - R') ----
    float ca = 0.f;
    const int rgrp = tid >> 3;
    const int lpos = tid & 7;
#pragma unroll
    for (int rr = 0; rr < 4; ++rr) {
        const int row = rr * 32 + rgrp;
        const unsigned short* rip = Rin + (size_t)(row0 + row) * 1024;
        unsigned short*       rop = Rout + (size_t)(row0 + row) * 1024;
        const float* crow = cb + ((size_t)q * NCODE + idxbuf[row]) * HDIM;
        const unsigned short* zp = LAST ? (zsrc + (size_t)(row0 + row) * 1024) : nullptr;
#pragma unroll
        for (int j = 0; j < 8; ++j) {
            const int g = lpos + j * 8;                 // k-chunk 0..63 (8 elems)
            const size_t off = (size_t)(g >> 1) * 32 + (size_t)(g & 1) * 8;
            half8 rh = *reinterpret_cast<const half8*>(rip + off);
            half8 rl = *reinterpret_cast<const half8*>(rip + off + 16);
            float4 c0 = *reinterpret_cast<const float4*>(crow + g * 8);
            float4 c1 = *reinterpret_cast<const float4*>(crow + g * 8 + 4);
            float cv[8] = {c0.x, c0.y, c0.z, c0.w, c1.x, c1.y, c1.z, c1.w};
            half8 zh, zl;
            if constexpr (LAST) {
                zh = *reinterpret_cast<const half8*>(zp + off);
                zl = *reinterpret_cast<const half8*>(zp + off + 16);
            }
            half8 oh, ol;
#pragma unroll
            for (int e = 0; e < 8; ++e) {
                float rv = (float)rh[e] + (float)rl[e];
                float d = rv - cv[e];
                ca = fmaf(d, d, ca);
                float ov = d;
                if constexpr (LAST) {
                    float zv = (float)zh[e] + (float)zl[e];
                    ov = zv - d;
                }
                _Float16 hv = (_Float16)ov;
                oh[e] = hv;
                ol[e] = (_Float16)(ov - (float)hv);
            }
            *reinterpret_cast<half8*>(rop + off)      = oh;
            *reinterpret_cast<half8*>(rop + off + 16) = ol;
        }
    }

    red[tid] = ca;
    __syncthreads();
    for (int s = 128; s > 0; s >>= 1) {
        if (tid < s) red[tid] += red[tid + s];
        __syncthreads();
    }
    if (tid == 0) commitP[q * 512 + blockIdx.x] = red[0];
}

// ---------------------------------------------------------------------------
__global__ __launch_bounds__(256)
void loss_reduce(const float* __restrict__ cP, int nc,
                 const float* __restrict__ rP, int nr,
                 float* __restrict__ out2)
{
    __shared__ float red[256];
    const int tid = threadIdx.x;

    float s = 0.f;
    for (int i = tid; i < nc; i += 256) s += cP[i];
    red[tid] = s;
    __syncthreads();
    for (int st = 128; st > 0; st >>= 1) {
        if (tid < st) red[tid] += red[tid + st];
        __syncthreads();
    }
    float ctot = red[0];
    __syncthreads();

    s = 0.f;
    for (int i = tid; i < nr; i += 256) s += rP[i];
    red[tid] = s;
    __syncthreads();
    for (int st = 128; st > 0; st >>= 1) {
        if (tid < st) red[tid] += red[tid + st];
        __syncthreads();
    }
    if (tid == 0) {
        out2[0] = red[0] / ((float)BATCH * (float)EDIM);
        out2[1] = 0.25f * ctot / ((float)BATCH * (float)HDIM);
    }
}

// ---------------------------------------------------------------------------
extern "C" void kernel_launch(void* const* d_in, const int* in_sizes, int n_in,
                              void* d_out, int out_size, void* d_ws, size_t ws_size,
                              hipStream_t stream)
{
    const float* x   = (const float*)d_in[0];
    const float* ew1 = (const float*)d_in[1];
    const float* eb1 = (const float*)d_in[2];
    const float* ew2 = (const float*)d_in[3];
    const float* eb2 = (const float*)d_in[4];
    const float* cb  = (const float*)d_in[5];
    const float* dw1 = (const float*)d_in[6];
    const float* db1 = (const float*)d_in[7];
    const float* dw2 = (const float*)d_in[8];
    const float* db2 = (const float*)d_in[9];

    float* out = (float*)d_out;
    float* ws  = (float*)d_ws;
    unsigned short* P0  = (unsigned short*)(ws + WS_P0);
    unsigned short* P1  = (unsigned short*)(ws + WS_P1);
    unsigned short* XS  = P1;                    // x-split aliased into P1 (dead before enc2 writes)
    unsigned short* cbs = (unsigned short*)(ws + WS_CBSPL);
    float* cn = ws + WS_CNORM;
    float* cP = ws + WS_COMMITP;
    float* rP = ws + WS_RECONP;
    unsigned short* w1s = (unsigned short*)(ws + WS_W1S);
    unsigned short* w2s = (unsigned short*)(ws + WS_W2S);
    unsigned short* w3s = (unsigned short*)(ws + WS_W3S);
    unsigned short* w4s = (unsigned short*)(ws + WS_W4S);

    // prep
    cnorm_kernel<<<NQ * NCODE, 64, 0, stream>>>(cb, cn);
    split_cb<<<256, 256, 0, stream>>>(cb, cbs);
    split_x<<<BATCH * 48 / 256, 256, 0, stream>>>(x, XS);
    split_w<<<(EDIM / 16) * 2 * HDIM / 256, 256, 0, stream>>>(ew1, w1s, HDIM, EDIM);
    split_w<<<(HDIM / 16) * 2 * HDIM / 256, 256, 0, stream>>>(ew2, w2s, HDIM, HDIM);
    split_w<<<(HDIM / 16) * 2 * HDIM / 256, 256, 0, stream>>>(dw1, w3s, HDIM, HDIM);
    split_w<<<(HDIM / 16) * 2 * EDIM / 256, 256, 0, stream>>>(dw2, w4s, EDIM, HDIM);

    // encoder
    gemm_pl<256, 24, 0, true><<<dim3(HDIM / 256, BATCH / 128), 256, 0, stream>>>(
        XS, w1s, eb1, P0, nullptr, nullptr, HDIM);
    gemm_pl<256, 32, 0, false><<<dim3(HDIM / 256, BATCH / 128), 256, 0, stream>>>(
        P0, w2s, eb2, P1, nullptr, nullptr, HDIM);

    // residual VQ (P1 = z split; residual ping in P0; quant -> P1)
    float* idxo = out + OUT_IDX_OFF;
    vq_stage<false><<<512, 256, 0, stream>>>(0, P1, P0, nullptr, cbs, cb, cn, idxo, cP);
    vq_stage<false><<<512, 256, 0, stream>>>(1, P0, P0, nullptr, cbs, cb, cn, idxo, cP);
    vq_stage<false><<<512, 256, 0, stream>>>(2, P0, P0, nullptr, cbs, cb, cn, idxo, cP);
    vq_stage<true ><<<512, 256, 0, stream>>>(3, P0, P1, P1,      cbs, cb, cn, idxo, cP);

    // decoder
    gemm_pl<256, 32, 0, true><<<dim3(HDIM / 256, BATCH / 128), 256, 0, stream>>>(
        P1, w3s, db1, P0, nullptr, nullptr, HDIM);
    gemm_pl<128, 32, 1, false><<<dim3(EDIM / 128, BATCH / 128), 256, 0, stream>>>(
        P0, w4s, db2, out, x, rP, EDIM);

    // losses
    loss_reduce<<<1, 256, 0, stream>>>(cP, NQ * 512, rP,
                                       (BATCH / 128) * (EDIM / 128),
                                       out + OUT_RL_OFF);
}